// Round 16
// baseline (2760.769 us; speedup 1.0000x reference)
//
#include <hip/hip_runtime.h>
#include <math.h>

#define HID   512
#define SEQL  256
#define BATCH 2048
#define NCLS  10
#define NB    16     // batch columns per WG = full MFMA tile width
#define H8S   552    // bytes per fp8 h row in LDS: 552/4 = 138 = 10 mod 32
                     // -> 16 cols hit 16 distinct banks (R7/R11-proven)

typedef _Float16 f16x8 __attribute__((ext_vector_type(8)));
typedef _Float16 f16x4 __attribute__((ext_vector_type(4)));
typedef _Float16 f16x2 __attribute__((ext_vector_type(2)));
typedef float    f32x4 __attribute__((ext_vector_type(4)));
typedef int      i32x4 __attribute__((ext_vector_type(4)));
typedef int      i32x8 __attribute__((ext_vector_type(8)));
typedef long     i64;
typedef long     i64x2 __attribute__((ext_vector_type(2)));

__device__ __forceinline__ float fsig(float v)  { return 1.f / (1.f + __expf(-v)); }
__device__ __forceinline__ float ftanh(float v) { return 1.f - 2.f / (1.f + __expf(2.f * v)); }

// e2m1 nearest-round quantize of y (pre-scaled); grid {0,.5,1,1.5,2,3,4,6}.
__device__ __forceinline__ unsigned q4(float y) {
    const unsigned s = (y < 0.f) ? 8u : 0u;
    const float a = fabsf(y);
    const unsigned c = a < 0.25f ? 0u : a < 0.75f ? 1u : a < 1.25f ? 2u :
                       a < 1.75f ? 3u : a < 2.5f  ? 4u : a < 3.5f  ? 5u :
                       a < 5.0f  ? 6u : 7u;
    return s | c;
}

// ---- g-gate: fp8 chunk-pair fragments (R7 machinery, 1 gate) -------------
// wqg[(((wv*4+sc)*4+pi)*2+h)*64 + lane] : uint4 = A-frags for row-tile
// p = wv+8*pi, K=32 subchunks m0=4sc+2h (bytes 0-7), m1=m0+1 (bytes 8-15).
__global__ void pack_g(const float* __restrict__ wg, uint4* __restrict__ wqg)
{
    const int idx = blockIdx.x * 256 + threadIdx.x;   // 16384
    const int lane = idx & 63;
    const int h  = (idx >> 6) & 1;
    const int pi = (idx >> 7) & 3;
    const int sc = (idx >> 9) & 3;
    const int wv = idx >> 11;
    const int j = 16 * (wv + 8 * pi) + (lane & 15);
    unsigned dw[4];
    #pragma unroll
    for (int d = 0; d < 4; d++) {
        float f[4];
        #pragma unroll
        for (int e = 0; e < 4; e++) {
            const int v = 4 * d + e;
            const int k = (4 * sc + 2 * h + (v >> 3)) * 32 + (lane >> 4) * 8 + (v & 7);
            f[e] = wg[j * HID + k] * 128.f;
        }
        int pk = __builtin_amdgcn_cvt_pk_fp8_f32(f[0], f[1], 0, false);
        pk     = __builtin_amdgcn_cvt_pk_fp8_f32(f[2], f[3], pk, true);
        dw[d] = (unsigned)pk;
    }
    wqg[idx] = make_uint4(dw[0], dw[1], dw[2], dw[3]);
}

// ---- i/f/o: fp4 K=128 fragments (R8/R9 machinery, 3 gates) ---------------
// wq4[((wv*4+sc)*12 + t12)*64 + lane], t12 = gt*4+pi (gt: 0=i,1=f,2=o).
__global__ void pack_ifo(const float* __restrict__ wi, const float* __restrict__ wf,
                         const float* __restrict__ wo, i32x4* __restrict__ wq4)
{
    const int idx = blockIdx.x * 256 + threadIdx.x;   // 24576
    const int lane = idx & 63, blk = idx >> 6;
    const int t12 = blk % 12, r = blk / 12;
    const int sc = r & 3, wv = r >> 2;
    const int gt = t12 >> 2, pi = t12 & 3;
    const int j = 16 * (wv + 8 * pi) + (lane & 15);
    const int kbase = 128 * sc + (lane >> 4) * 32;
    const float* w = (gt == 0) ? wi : (gt == 1) ? wf : wo;
    int dw[4];
    #pragma unroll
    for (int d = 0; d < 4; d++) {
        unsigned u = 0;
        #pragma unroll
        for (int by = 0; by < 4; by++) {
            const int e0 = 8 * d + 2 * by;
            const unsigned c0 = q4(w[j * HID + kbase + e0]     * 1024.f);
            const unsigned c1 = q4(w[j * HID + kbase + e0 + 1] * 1024.f);
            u |= (c0 | (c1 << 4)) << (8 * by);
        }
        dw[d] = (int)u;
    }
    wq4[idx] = (i32x4){dw[0], dw[1], dw[2], dw[3]};
}

// MFMA via inline asm with "+a": C/D in AGPRs (R15-proven — killed the
// R9-R13 spill cascade; VGPR 120, WRITE 80B).
__device__ __forceinline__ void mma8a(f32x4& c, i64 a, i64 b) {
    asm volatile("v_mfma_f32_16x16x32_fp8_fp8 %0, %1, %2, %0"
                 : "+a"(c) : "v"(a), "v"(b));
}
// Non-scaled f8f6f4 MFMA: cbsz:4 = A fp4 (4-reg tuple), B fp8 (8-reg).
__device__ __forceinline__ void mma4a(f32x4& c, i32x4 a, i32x8 b) {
    asm volatile("v_mfma_f32_16x16x128_f8f6f4 %0, %1, %2, %0 cbsz:4"
                 : "+a"(c) : "v"(a), "v"(b));
}
// 32-B fp8 B-operand from LDS as 4 x ds_read_b64 (8B-aligned at H8S=552).
__device__ __forceinline__ i32x8 ld_h128(const char* p) {
    union { i64 q[4]; i32x8 v; } u;
    u.q[0] = *(const i64*)(p);
    u.q[1] = *(const i64*)(p + 8);
    u.q[2] = *(const i64*)(p + 16);
    u.q[3] = *(const i64*)(p + 24);
    return u.v;
}

// Persistent mixed-precision MFMA LSTM (R15 + distance-2 weight prefetch).
// R15 post-mortem: time = F + N*6.25ns/load with implied concurrency only
// ~13 loads/CU — rolling buffers reused at ~250-350cyc, marginal vs ~200cyc
// L2 latency. This version splits the buffers (QL/QH, GpA/GpB, +40 VGPR,
// demand ~160V+64A <= 256 @ 2 waves/EU) so every load issues a FULL
// super-chunk (~700cyc) before use. Discriminates MLP-bound vs TA-bound.
__global__ __launch_bounds__(512, 1) void lstm_mfma(
    const float* __restrict__ x,                                   // [B][SEQ]
    const uint4* __restrict__ wqg, const i32x4* __restrict__ wq4,  // packed w
    const float* __restrict__ wgx, const float* __restrict__ wix,
    const float* __restrict__ wfx, const float* __restrict__ wox,  // [H]
    const float* __restrict__ bg,  const float* __restrict__ bi,
    const float* __restrict__ bf_, const float* __restrict__ bo,   // [H]
    const float* __restrict__ wph, const float* __restrict__ bp,   // [C][H], [C]
    const float* __restrict__ h_init, const float* __restrict__ c_init, // [H]
    float* __restrict__ out)                                       // [B][C]
{
    __shared__ __align__(16) char     h8s[2][NB * H8S];   // 17.3 KB fp8 h (x128)
    __shared__ float x_s[NB][SEQL + 1];                   // 16.4 KB
    __shared__ __align__(16) _Float16 hfin[NB][HID];      // 16 KB (final h only)

    const int tid  = threadIdx.x;
    const int lane = tid & 63;
    const int wv   = tid >> 6;
    const int col  = lane & 15;
    const int kq   = lane >> 4;
    const int b0   = blockIdx.x * NB;
    const int gbase = wv * 2048 + lane;   // uint4 units
    const int qbase = wv * 3072 + lane;   // i32x4 units

    for (int i = tid; i < NB * SEQL; i += 512)
        x_s[i >> 8][i & 255] = x[(b0 + (i >> 8)) * SEQL + (i & 255)];

    for (int i = tid; i < 2 * NB * H8S; i += 512) {
        const int b = i / (NB * H8S), k = (i % (NB * H8S)) % H8S;
        const float v = (b == 0 && k < HID) ? h_init[k] * 128.f : 0.f;
        const int pk = __builtin_amdgcn_cvt_pk_fp8_f32(v, 0.f, 0, false);
        ((char*)h8s)[i] = (char)(pk & 0xff);
    }

    const int j00 = 16 * wv + 4 * kq;     // + 128*pi per tile row-block
    f32x4 creg[4];
    #pragma unroll
    for (int pi = 0; pi < 4; pi++) creg[pi] = *(const f32x4*)&c_init[j00 + 128 * pi];

    // Seed A: acc a: 0-3 = g(pi), 4+t12 = ifo. F = {wx*sc, b*sc/256} f16x2;
    // with Bs = {x_t, 256} this yields acc = (wx*x + b) * sc. kq==0 lanes only.
    unsigned sv[16];
    {
        const float* gxp[4] = {wgx, wix, wfx, wox};
        const float* bpt[4] = {bg, bi, bf_, bo};
        #pragma unroll
        for (int a = 0; a < 16; a++) {
            const int pi = (a < 4) ? a : ((a - 4) & 3);
            const int gs = (a < 4) ? 0 : 1 + ((a - 4) >> 2);
            const int j  = 16 * (wv + 8 * pi) + col;
            const float sc  = (a < 4) ? 16384.f : 131072.f;
            f16x2 pr;
            pr[0] = (_Float16)(gxp[gs][j] * sc);
            pr[1] = (_Float16)(bpt[gs][j] * sc * (1.f / 256.f));
            sv[a] = (kq == 0) ? __builtin_bit_cast(unsigned, pr) : 0u;
        }
    }

    __syncthreads();

    // Distance-2 rolling buffers: GpA/GpB (g h0/h1 halves), QL/QH (ifo
    // lo/hi tile-sixes). Each is loaded for sc+1 right after its use in sc.
    uint4 GpA[4], GpB[4];
    i32x4 QL[6], QH[6];
    #pragma unroll
    for (int pi = 0; pi < 4; pi++) {
        GpA[pi] = wqg[gbase + (pi * 2 + 0) * 64];
        GpB[pi] = wqg[gbase + (pi * 2 + 1) * 64];
    }
    #pragma unroll
    for (int q6 = 0; q6 < 6; q6++) {
        QL[q6] = wq4[qbase + q6 * 64];
        QH[q6] = wq4[qbase + (6 + q6) * 64];
    }

    int toff = 0;   // always 0, but unprovably so after laundering

    #pragma unroll 1
    for (int t = 0; t < SEQL; t++) {
        const int rb = t & 1, wb = rb ^ 1;
        const char* hb8 = &h8s[rb][col * H8S];

        // Anti-LICM: make weight addresses opaque for this iteration.
        asm volatile("" : "+v"(toff));
        const uint4* __restrict__ wqg_t = wqg + toff;
        const i32x4* __restrict__ wq4_t = wq4 + toff;

        // Seed MFMA: acc = (wx*x_t + b) * per-gate scale.
        f16x8 Bs = {};
        if (kq == 0) { Bs[0] = (_Float16)x_s[col][t]; Bs[1] = (_Float16)256.f; }
        f32x4 acc[16];
        #pragma unroll
        for (int a = 0; a < 16; a++) {
            const f16x2 pr = __builtin_bit_cast(f16x2, sv[a]);
            f16x8 F = {};
            F[0] = pr[0]; F[1] = pr[1];
            acc[a] = __builtin_amdgcn_mfma_f32_16x16x32_f16(
                F, Bs, (f32x4){0.f, 0.f, 0.f, 0.f}, 0, 0, 0);
        }

        #pragma unroll
        for (int sc = 0; sc < 4; sc++) {
            const int scn = (sc + 1) & 3;   // wrap: sc=3 prefetches next step's sc=0
            // [1] g h0: subchunks 4sc+0/1 with GpA (holds (sc,h0)).
            {
                const i64 Bm0 = *(const i64*)(hb8 + (4 * sc + 0) * 32 + kq * 8);
                const i64 Bm1 = *(const i64*)(hb8 + (4 * sc + 1) * 32 + kq * 8);
                #pragma unroll
                for (int pi = 0; pi < 4; pi++) {
                    const i64x2 gv = __builtin_bit_cast(i64x2, GpA[pi]);
                    mma8a(acc[pi], gv.x, Bm0);
                    mma8a(acc[pi], gv.y, Bm1);
                }
            }
            // [2] GpA <- (scn, h0)   — next use: next sc's [1] (~7 blocks)
            #pragma unroll
            for (int pi = 0; pi < 4; pi++)
                GpA[pi] = wqg_t[gbase + (scn * 8 + pi * 2 + 0) * 64];
            // [3] ifo lo: t12 0..5 with QL (holds sc lo).
            const i32x8 Bv = ld_h128(hb8 + sc * 128 + kq * 32);
            #pragma unroll
            for (int q6 = 0; q6 < 6; q6++)
                mma4a(acc[4 + q6], QL[q6], Bv);
            // [4] QL <- (scn) lo     — next use: next sc's [3]
            #pragma unroll
            for (int q6 = 0; q6 < 6; q6++)
                QL[q6] = wq4_t[qbase + (scn * 12 + q6) * 64];
            // [5] g h1: subchunks 4sc+2/3 with GpB (holds (sc,h1)).
            {
                const i64 Bm2 = *(const i64*)(hb8 + (4 * sc + 2) * 32 + kq * 8);
                const i64 Bm3 = *(const i64*)(hb8 + (4 * sc + 3) * 32 + kq * 8);
                #pragma unroll
                for (int pi = 0; pi < 4; pi++) {
                    const i64x2 gv = __builtin_bit_cast(i64x2, GpB[pi]);
                    mma8a(acc[pi], gv.x, Bm2);
                    mma8a(acc[pi], gv.y, Bm3);
                }
            }
            // [6] GpB <- (scn, h1)   — next use: next sc's [5]
            #pragma unroll
            for (int pi = 0; pi < 4; pi++)
                GpB[pi] = wqg_t[gbase + (scn * 8 + pi * 2 + 1) * 64];
            // [7] ifo hi: t12 6..11 with QH (holds sc hi).
            #pragma unroll
            for (int q6 = 0; q6 < 6; q6++)
                mma4a(acc[10 + q6], QH[q6], Bv);
            // [8] QH <- (scn) hi     — next use: next sc's [7]
            #pragma unroll
            for (int q6 = 0; q6 < 6; q6++)
                QH[q6] = wq4_t[qbase + (scn * 12 + 6 + q6) * 64];
        }

        // MFMA->VALU read hazard fence: asm MFMAs are opaque to the hazard
        // recognizer; carry a data dep on the last-written accs + 16 nops.
        asm volatile("s_nop 7\n\ts_nop 7"
                     : "+a"(acc[12]), "+a"(acc[13]), "+a"(acc[14]), "+a"(acc[15]));

        // Nonlinearity: g acc = preact*2^14, ifo acc = preact*2^17 (bias incl.)
        const float S14 = 1.f / 16384.f, S17 = 1.f / 131072.f;
        #pragma unroll
        for (int pi = 0; pi < 4; pi++) {
            const int j0 = j00 + 128 * pi;
            float hr[4];
            #pragma unroll
            for (int r = 0; r < 4; r++) {
                const float g  = ftanh(acc[pi][r]      * S14);
                const float ii = fsig (acc[4 + pi][r]  * S17);
                const float ff = fsig (acc[8 + pi][r]  * S17);
                const float oo = fsig (acc[12 + pi][r] * S17);
                const float cc = fmaf(g, ii, creg[pi][r] * ff);
                creg[pi][r] = cc;
                hr[r] = ftanh(cc) * oo;
            }
            int pk = __builtin_amdgcn_cvt_pk_fp8_f32(hr[0] * 128.f, hr[1] * 128.f, 0, false);
            pk     = __builtin_amdgcn_cvt_pk_fp8_f32(hr[2] * 128.f, hr[3] * 128.f, pk, true);
            *(unsigned*)&h8s[wb][col * H8S + j0] = (unsigned)pk;
            if (t == SEQL - 1) {
                f16x4 hv;
                #pragma unroll
                for (int r = 0; r < 4; r++) hv[r] = (_Float16)hr[r];
                *(f16x4*)&hfin[col][j0] = hv;
            }
        }
        __syncthreads();
    }

    // Epilogue: out[b][cls] = bp[cls] + sum_k wph[cls][k] * h_final[k][b]
    if (tid < NB * NCLS) {
        const int c = tid / NCLS, cls = tid - c * NCLS;
        float s = bp[cls];
        for (int k = 0; k < HID; k++)
            s = fmaf(wph[cls * HID + k], (float)hfin[c][k], s);
        out[(b0 + c) * NCLS + cls] = s;
    }
}

extern "C" void kernel_launch(void* const* d_in, const int* in_sizes, int n_in,
                              void* d_out, int out_size, void* d_ws, size_t ws_size,
                              hipStream_t stream)
{
    const float* x   = (const float*)d_in[0];
    const float* wgx = (const float*)d_in[1];
    const float* wix = (const float*)d_in[2];
    const float* wfx = (const float*)d_in[3];
    const float* wox = (const float*)d_in[4];
    const float* wgh = (const float*)d_in[5];
    const float* wih = (const float*)d_in[6];
    const float* wfh = (const float*)d_in[7];
    const float* woh = (const float*)d_in[8];
    const float* bg  = (const float*)d_in[9];
    const float* bi  = (const float*)d_in[10];
    const float* bf  = (const float*)d_in[11];
    const float* bo  = (const float*)d_in[12];
    const float* wph = (const float*)d_in[13];
    const float* bp  = (const float*)d_in[14];
    const float* h0  = (const float*)d_in[15];
    const float* c0  = (const float*)d_in[16];
    float* out = (float*)d_out;

    char* ws = (char*)d_ws;
    uint4* wqg = (uint4*)ws;                     // [0, 256K): g fp8 pair frags
    i32x4* wq4 = (i32x4*)(ws + (256u << 10));    // [256K, 640K): ifo fp4 frags

    pack_g  <<<dim3(64), dim3(256), 0, stream>>>(wgh, wqg);
    pack_ifo<<<dim3(96), dim3(256), 0, stream>>>(wih, wfh, woh, wq4);
    lstm_mfma<<<dim3(BATCH / NB), dim3(512), 0, stream>>>(
        x, wqg, wq4, wgx, wix, wfx, wox, bg, bi, bf, bo, wph, bp, h0, c0, out);
}

// Round 17
// 2381.433 us; speedup vs baseline: 1.1593x; 1.1593x over previous
//
#include <hip/hip_runtime.h>
#include <math.h>

#define HID   512
#define SEQL  256
#define BATCH 2048
#define NCLS  10
#define NB    16     // batch columns per WG = full MFMA tile width
#define H8S   552    // bytes per fp8 h row in LDS: 552/4 = 138 = 10 mod 32
                     // -> 16 cols hit 16 distinct banks (R7/R11-proven)

typedef _Float16 f16x8 __attribute__((ext_vector_type(8)));
typedef _Float16 f16x4 __attribute__((ext_vector_type(4)));
typedef _Float16 f16x2 __attribute__((ext_vector_type(2)));
typedef float    f32x4 __attribute__((ext_vector_type(4)));
typedef int      i32x4 __attribute__((ext_vector_type(4)));
typedef int      i32x8 __attribute__((ext_vector_type(8)));
typedef long     i64;
typedef long     i64x2 __attribute__((ext_vector_type(2)));

__device__ __forceinline__ float fsig(float v)  { return 1.f / (1.f + __expf(-v)); }
__device__ __forceinline__ float ftanh(float v) { return 1.f - 2.f / (1.f + __expf(2.f * v)); }

// AGPR-home helpers (R16 post-mortem: arch-V cap is hard at 128; creg/sv
// move to the AGPR file to fund the deeper fp4 prefetch within budget).
__device__ __forceinline__ void agw(float& a, float v) {
    asm volatile("v_accvgpr_write_b32 %0, %1" : "=a"(a) : "v"(v));
}
__device__ __forceinline__ float agr(const float& a) {
    float r; asm volatile("v_accvgpr_read_b32 %0, %1" : "=v"(r) : "a"(a)); return r;
}
__device__ __forceinline__ void agwu(unsigned& a, unsigned v) {
    asm volatile("v_accvgpr_write_b32 %0, %1" : "=a"(a) : "v"(v));
}
__device__ __forceinline__ unsigned agru(const unsigned& a) {
    unsigned r; asm volatile("v_accvgpr_read_b32 %0, %1" : "=v"(r) : "a"(a)); return r;
}

// e2m1 nearest-round quantize of y (pre-scaled); grid {0,.5,1,1.5,2,3,4,6}.
__device__ __forceinline__ unsigned q4(float y) {
    const unsigned s = (y < 0.f) ? 8u : 0u;
    const float a = fabsf(y);
    const unsigned c = a < 0.25f ? 0u : a < 0.75f ? 1u : a < 1.25f ? 2u :
                       a < 1.75f ? 3u : a < 2.5f  ? 4u : a < 3.5f  ? 5u :
                       a < 5.0f  ? 6u : 7u;
    return s | c;
}

// ---- g-gate: fp8 chunk-pair fragments (R7 machinery, 1 gate) -------------
// wqg[(((wv*4+sc)*4+pi)*2+h)*64 + lane] : uint4 = A-frags for row-tile
// p = wv+8*pi, K=32 subchunks m0=4sc+2h (bytes 0-7), m1=m0+1 (bytes 8-15).
__global__ void pack_g(const float* __restrict__ wg, uint4* __restrict__ wqg)
{
    const int idx = blockIdx.x * 256 + threadIdx.x;   // 16384
    const int lane = idx & 63;
    const int h  = (idx >> 6) & 1;
    const int pi = (idx >> 7) & 3;
    const int sc = (idx >> 9) & 3;
    const int wv = idx >> 11;
    const int j = 16 * (wv + 8 * pi) + (lane & 15);
    unsigned dw[4];
    #pragma unroll
    for (int d = 0; d < 4; d++) {
        float f[4];
        #pragma unroll
        for (int e = 0; e < 4; e++) {
            const int v = 4 * d + e;
            const int k = (4 * sc + 2 * h + (v >> 3)) * 32 + (lane >> 4) * 8 + (v & 7);
            f[e] = wg[j * HID + k] * 128.f;
        }
        int pk = __builtin_amdgcn_cvt_pk_fp8_f32(f[0], f[1], 0, false);
        pk     = __builtin_amdgcn_cvt_pk_fp8_f32(f[2], f[3], pk, true);
        dw[d] = (unsigned)pk;
    }
    wqg[idx] = make_uint4(dw[0], dw[1], dw[2], dw[3]);
}

// ---- i/f/o: fp4 K=128 fragments (R8/R9 machinery, 3 gates) ---------------
// wq4[((wv*4+sc)*12 + t12)*64 + lane], t12 = gt*4+pi (gt: 0=i,1=f,2=o).
__global__ void pack_ifo(const float* __restrict__ wi, const float* __restrict__ wf,
                         const float* __restrict__ wo, i32x4* __restrict__ wq4)
{
    const int idx = blockIdx.x * 256 + threadIdx.x;   // 24576
    const int lane = idx & 63, blk = idx >> 6;
    const int t12 = blk % 12, r = blk / 12;
    const int sc = r & 3, wv = r >> 2;
    const int gt = t12 >> 2, pi = t12 & 3;
    const int j = 16 * (wv + 8 * pi) + (lane & 15);
    const int kbase = 128 * sc + (lane >> 4) * 32;
    const float* w = (gt == 0) ? wi : (gt == 1) ? wf : wo;
    int dw[4];
    #pragma unroll
    for (int d = 0; d < 4; d++) {
        unsigned u = 0;
        #pragma unroll
        for (int by = 0; by < 4; by++) {
            const int e0 = 8 * d + 2 * by;
            const unsigned c0 = q4(w[j * HID + kbase + e0]     * 1024.f);
            const unsigned c1 = q4(w[j * HID + kbase + e0 + 1] * 1024.f);
            u |= (c0 | (c1 << 4)) << (8 * by);
        }
        dw[d] = (int)u;
    }
    wq4[idx] = (i32x4){dw[0], dw[1], dw[2], dw[3]};
}

// MFMA via inline asm with "+a": C/D in AGPRs (R15-proven — killed the
// R9-R13 spill cascade; VGPR 120, WRITE 80B).
__device__ __forceinline__ void mma8a(f32x4& c, i64 a, i64 b) {
    asm volatile("v_mfma_f32_16x16x32_fp8_fp8 %0, %1, %2, %0"
                 : "+a"(c) : "v"(a), "v"(b));
}
// Non-scaled f8f6f4 MFMA: cbsz:4 = A fp4 (4-reg tuple), B fp8 (8-reg).
__device__ __forceinline__ void mma4a(f32x4& c, i32x4 a, i32x8 b) {
    asm volatile("v_mfma_f32_16x16x128_f8f6f4 %0, %1, %2, %0 cbsz:4"
                 : "+a"(c) : "v"(a), "v"(b));
}
// 32-B fp8 B-operand from LDS as 4 x ds_read_b64 (8B-aligned at H8S=552).
__device__ __forceinline__ i32x8 ld_h128(const char* p) {
    union { i64 q[4]; i32x8 v; } u;
    u.q[0] = *(const i64*)(p);
    u.q[1] = *(const i64*)(p + 8);
    u.q[2] = *(const i64*)(p + 16);
    u.q[3] = *(const i64*)(p + 24);
    return u.v;
}

// Persistent mixed-precision MFMA LSTM (R15 + fp4 distance-2 prefetch,
// funded by AGPR-homing creg/sv). R16 post-mortem: +40 arch-V overflowed
// the 128 cap -> mild spill, regression. This version: creg[16]+sv[16]
// -> AGPR (-32 V), Qh -> QL/QH (+24 V), net ~112 V + 96 A. fp4 loads
// (60% of stream) now issue 4-6 blocks (~500cyc) before use.
// Discriminates MLP-bound (expect 1950-2150us) vs TA-bound (unchanged).
__global__ __launch_bounds__(512, 1) void lstm_mfma(
    const float* __restrict__ x,                                   // [B][SEQ]
    const uint4* __restrict__ wqg, const i32x4* __restrict__ wq4,  // packed w
    const float* __restrict__ wgx, const float* __restrict__ wix,
    const float* __restrict__ wfx, const float* __restrict__ wox,  // [H]
    const float* __restrict__ bg,  const float* __restrict__ bi,
    const float* __restrict__ bf_, const float* __restrict__ bo,   // [H]
    const float* __restrict__ wph, const float* __restrict__ bp,   // [C][H], [C]
    const float* __restrict__ h_init, const float* __restrict__ c_init, // [H]
    float* __restrict__ out)                                       // [B][C]
{
    __shared__ __align__(16) char     h8s[2][NB * H8S];   // 17.3 KB fp8 h (x128)
    __shared__ float x_s[NB][SEQL + 1];                   // 16.4 KB
    __shared__ __align__(16) _Float16 hfin[NB][HID];      // 16 KB (final h only)

    const int tid  = threadIdx.x;
    const int lane = tid & 63;
    const int wv   = tid >> 6;
    const int col  = lane & 15;
    const int kq   = lane >> 4;
    const int b0   = blockIdx.x * NB;
    const int gbase = wv * 2048 + lane;   // uint4 units
    const int qbase = wv * 3072 + lane;   // i32x4 units

    for (int i = tid; i < NB * SEQL; i += 512)
        x_s[i >> 8][i & 255] = x[(b0 + (i >> 8)) * SEQL + (i & 255)];

    for (int i = tid; i < 2 * NB * H8S; i += 512) {
        const int b = i / (NB * H8S), k = (i % (NB * H8S)) % H8S;
        const float v = (b == 0 && k < HID) ? h_init[k] * 128.f : 0.f;
        const int pk = __builtin_amdgcn_cvt_pk_fp8_f32(v, 0.f, 0, false);
        ((char*)h8s)[i] = (char)(pk & 0xff);
    }

    const int j00 = 16 * wv + 4 * kq;     // + 128*pi per tile row-block

    // Cell state, AGPR-homed: cra[pi*4+r].
    float cra[16];
    #pragma unroll
    for (int pi = 0; pi < 4; pi++) {
        const f32x4 cv = *(const f32x4*)&c_init[j00 + 128 * pi];
        #pragma unroll
        for (int r = 0; r < 4; r++) agw(cra[pi * 4 + r], cv[r]);
    }

    // Seed A, AGPR-homed: acc a: 0-3 = g(pi), 4+t12 = ifo.
    // F = {wx*sc, b*sc/256} f16x2; with Bs = {x_t, 256} the seed MFMA yields
    // acc = (wx*x + b) * sc. kq==0 lanes only.
    unsigned sva[16];
    {
        const float* gxp[4] = {wgx, wix, wfx, wox};
        const float* bpt[4] = {bg, bi, bf_, bo};
        #pragma unroll
        for (int a = 0; a < 16; a++) {
            const int pi = (a < 4) ? a : ((a - 4) & 3);
            const int gs = (a < 4) ? 0 : 1 + ((a - 4) >> 2);
            const int j  = 16 * (wv + 8 * pi) + col;
            const float sc  = (a < 4) ? 16384.f : 131072.f;
            f16x2 pr;
            pr[0] = (_Float16)(gxp[gs][j] * sc);
            pr[1] = (_Float16)(bpt[gs][j] * sc * (1.f / 256.f));
            agwu(sva[a], (kq == 0) ? __builtin_bit_cast(unsigned, pr) : 0u);
        }
    }

    __syncthreads();

    // Weight buffers: Gp[4] (g, short-distance as in R15), QL/QH[6] (fp4,
    // distance-2: loaded one full super-chunk before use).
    uint4 Gp[4];
    i32x4 QL[6], QH[6];
    #pragma unroll
    for (int pi = 0; pi < 4; pi++) Gp[pi] = wqg[gbase + (pi * 2 + 0) * 64];
    #pragma unroll
    for (int q6 = 0; q6 < 6; q6++) {
        QL[q6] = wq4[qbase + q6 * 64];
        QH[q6] = wq4[qbase + (6 + q6) * 64];
    }

    int toff = 0;   // always 0, but unprovably so after laundering

    #pragma unroll 1
    for (int t = 0; t < SEQL; t++) {
        const int rb = t & 1, wb = rb ^ 1;
        const char* hb8 = &h8s[rb][col * H8S];

        // Anti-LICM: make weight addresses opaque for this iteration.
        asm volatile("" : "+v"(toff));
        const uint4* __restrict__ wqg_t = wqg + toff;
        const i32x4* __restrict__ wq4_t = wq4 + toff;

        // Seed MFMA: acc = (wx*x_t + b) * per-gate scale.
        f16x8 Bs = {};
        if (kq == 0) { Bs[0] = (_Float16)x_s[col][t]; Bs[1] = (_Float16)256.f; }
        f32x4 acc[16];
        #pragma unroll
        for (int a = 0; a < 16; a++) {
            const f16x2 pr = __builtin_bit_cast(f16x2, agru(sva[a]));
            f16x8 F = {};
            F[0] = pr[0]; F[1] = pr[1];
            acc[a] = __builtin_amdgcn_mfma_f32_16x16x32_f16(
                F, Bs, (f32x4){0.f, 0.f, 0.f, 0.f}, 0, 0, 0);
        }

        #pragma unroll
        for (int sc = 0; sc < 4; sc++) {
            const int scn = (sc + 1) & 3;   // wrap: sc=3 prefetches next step's sc=0
            // [1] g h0: subchunks 4sc+0/1 with Gp (holds (sc,h0)).
            {
                const i64 Bm0 = *(const i64*)(hb8 + (4 * sc + 0) * 32 + kq * 8);
                const i64 Bm1 = *(const i64*)(hb8 + (4 * sc + 1) * 32 + kq * 8);
                #pragma unroll
                for (int pi = 0; pi < 4; pi++) {
                    const i64x2 gv = __builtin_bit_cast(i64x2, Gp[pi]);
                    mma8a(acc[pi], gv.x, Bm0);
                    mma8a(acc[pi], gv.y, Bm1);
                }
            }
            // [2] Gp <- (sc, h1)
            #pragma unroll
            for (int pi = 0; pi < 4; pi++)
                Gp[pi] = wqg_t[gbase + (sc * 8 + pi * 2 + 1) * 64];
            // [3] ifo lo: t12 0..5 with QL (holds sc lo; loaded last sc).
            const i32x8 Bv = ld_h128(hb8 + sc * 128 + kq * 32);
            #pragma unroll
            for (int q6 = 0; q6 < 6; q6++)
                mma4a(acc[4 + q6], QL[q6], Bv);
            // [4] QL <- (scn) lo   — next use: next sc's [3] (~4 blocks)
            #pragma unroll
            for (int q6 = 0; q6 < 6; q6++)
                QL[q6] = wq4_t[qbase + (scn * 12 + q6) * 64];
            // [5] g h1: subchunks 4sc+2/3 with Gp (landed during [3]).
            {
                const i64 Bm2 = *(const i64*)(hb8 + (4 * sc + 2) * 32 + kq * 8);
                const i64 Bm3 = *(const i64*)(hb8 + (4 * sc + 3) * 32 + kq * 8);
                #pragma unroll
                for (int pi = 0; pi < 4; pi++) {
                    const i64x2 gv = __builtin_bit_cast(i64x2, Gp[pi]);
                    mma8a(acc[pi], gv.x, Bm2);
                    mma8a(acc[pi], gv.y, Bm3);
                }
            }
            // [6] Gp <- (scn, h0)
            #pragma unroll
            for (int pi = 0; pi < 4; pi++)
                Gp[pi] = wqg_t[gbase + (scn * 8 + pi * 2 + 0) * 64];
            // [7] ifo hi: t12 6..11 with QH (holds sc hi; loaded last sc).
            #pragma unroll
            for (int q6 = 0; q6 < 6; q6++)
                mma4a(acc[10 + q6], QH[q6], Bv);
            // [8] QH <- (scn) hi   — next use: next sc's [7] (~6 blocks)
            #pragma unroll
            for (int q6 = 0; q6 < 6; q6++)
                QH[q6] = wq4_t[qbase + (scn * 12 + 6 + q6) * 64];
        }

        // MFMA->VALU read hazard fence: asm MFMAs are opaque to the hazard
        // recognizer; carry a data dep on the last-written accs + 16 nops.
        asm volatile("s_nop 7\n\ts_nop 7"
                     : "+a"(acc[12]), "+a"(acc[13]), "+a"(acc[14]), "+a"(acc[15]));

        // Nonlinearity: g acc = preact*2^14, ifo acc = preact*2^17 (bias incl.)
        const float S14 = 1.f / 16384.f, S17 = 1.f / 131072.f;
        #pragma unroll
        for (int pi = 0; pi < 4; pi++) {
            const int j0 = j00 + 128 * pi;
            float hr[4];
            #pragma unroll
            for (int r = 0; r < 4; r++) {
                const float g  = ftanh(acc[pi][r]      * S14);
                const float ii = fsig (acc[4 + pi][r]  * S17);
                const float ff = fsig (acc[8 + pi][r]  * S17);
                const float oo = fsig (acc[12 + pi][r] * S17);
                const float cold = agr(cra[pi * 4 + r]);
                const float cc = fmaf(g, ii, cold * ff);
                agw(cra[pi * 4 + r], cc);
                hr[r] = ftanh(cc) * oo;
            }
            int pk = __builtin_amdgcn_cvt_pk_fp8_f32(hr[0] * 128.f, hr[1] * 128.f, 0, false);
            pk     = __builtin_amdgcn_cvt_pk_fp8_f32(hr[2] * 128.f, hr[3] * 128.f, pk, true);
            *(unsigned*)&h8s[wb][col * H8S + j0] = (unsigned)pk;
            if (t == SEQL - 1) {
                f16x4 hv;
                #pragma unroll
                for (int r = 0; r < 4; r++) hv[r] = (_Float16)hr[r];
                *(f16x4*)&hfin[col][j0] = hv;
            }
        }
        __syncthreads();
    }

    // Epilogue: out[b][cls] = bp[cls] + sum_k wph[cls][k] * h_final[k][b]
    if (tid < NB * NCLS) {
        const int c = tid / NCLS, cls = tid - c * NCLS;
        float s = bp[cls];
        for (int k = 0; k < HID; k++)
            s = fmaf(wph[cls * HID + k], (float)hfin[c][k], s);
        out[(b0 + c) * NCLS + cls] = s;
    }
}

extern "C" void kernel_launch(void* const* d_in, const int* in_sizes, int n_in,
                              void* d_out, int out_size, void* d_ws, size_t ws_size,
                              hipStream_t stream)
{
    const float* x   = (const float*)d_in[0];
    const float* wgx = (const float*)d_in[1];
    const float* wix = (const float*)d_in[2];
    const float* wfx = (const float*)d_in[3];
    const float* wox = (const float*)d_in[4];
    const float* wgh = (const float*)d_in[5];
    const float* wih = (const float*)d_in[6];
    const float* wfh = (const float*)d_in[7];
    const float* woh = (const float*)d_in[8];
    const float* bg  = (const float*)d_in[9];
    const float* bi  = (const float*)d_in[10];
    const float* bf  = (const float*)d_in[11];
    const float* bo  = (const float*)d_in[12];
    const float* wph = (const float*)d_in[13];
    const float* bp  = (const float*)d_in[14];
    const float* h0  = (const float*)d_in[15];
    const float* c0  = (const float*)d_in[16];
    float* out = (float*)d_out;

    char* ws = (char*)d_ws;
    uint4* wqg = (uint4*)ws;                     // [0, 256K): g fp8 pair frags
    i32x4* wq4 = (i32x4*)(ws + (256u << 10));    // [256K, 640K): ifo fp4 frags

    pack_g  <<<dim3(64), dim3(256), 0, stream>>>(wgh, wqg);
    pack_ifo<<<dim3(96), dim3(256), 0, stream>>>(wih, wfh, woh, wq4);
    lstm_mfma<<<dim3(BATCH / NB), dim3(512), 0, stream>>>(
        x, wqg, wq4, wgx, wix, wfx, wox, bg, bi, bf, bo, wph, bp, h0, c0, out);
}